// Round 3
// baseline (191908.545 us; speedup 1.0000x reference)
//
#include <hip/hip_runtime.h>
#include <math.h>

// ---------------------------------------------------------------------------
// helpers
// ---------------------------------------------------------------------------
__device__ __forceinline__ float sigm(float x) { return 1.0f / (1.0f + __expf(-x)); }

__device__ __forceinline__ float waveSum(float v) {
#pragma unroll
  for (int off = 32; off > 0; off >>= 1) v += __shfl_xor(v, off);
  return v;
}

// L2-scope (bypass L1, hit shared per-XCD L2) 8B load
__device__ __forceinline__ unsigned long long ld_sc0_u64(const unsigned long long* p) {
  unsigned long long v;
  asm volatile("global_load_dwordx2 %0, %1, off sc0\n\ts_waitcnt vmcnt(0)"
               : "=v"(v) : "v"(p) : "memory");
  return v;
}
// coherence-point (bypass L1+L2) 8B load — escalation path
__device__ __forceinline__ unsigned long long ld_sc01_u64(const unsigned long long* p) {
  unsigned long long v;
  asm volatile("global_load_dwordx2 %0, %1, off sc0 sc1\n\ts_waitcnt vmcnt(0)"
               : "=v"(v) : "v"(p) : "memory");
  return v;
}
// write-through-to-coherence-point 8B store (atomic as a single transaction)
__device__ __forceinline__ void st_thru_u64(unsigned long long* p, unsigned long long v) {
  asm volatile("global_store_dwordx2 %0, %1, off sc0 sc1" :: "v"(p), "v"(v) : "memory");
}

// ---------------------------------------------------------------------------
// char CNN + elmo concat  -> x_all (4224 x 356)
// ---------------------------------------------------------------------------
__global__ __launch_bounds__(128) void cnn_embed_kernel(
    const int* __restrict__ chars_ctx, const int* __restrict__ chars_qry,
    const float* __restrict__ elmo_ctx, const float* __restrict__ elmo_qry,
    const float* __restrict__ char_emb, const float* __restrict__ conv_w,
    const float* __restrict__ conv_b, float* __restrict__ x_all)
{
  int n = blockIdx.x;
  const int*   chars = (n < 4096) ? (chars_ctx + n * 16) : (chars_qry + (n - 4096) * 16);
  const float* elmo  = (n < 4096) ? (elmo_ctx + (size_t)n * 256)
                                  : (elmo_qry + (size_t)(n - 4096) * 256);
  __shared__ float xl[1600];   // [emb_dim=100][pos=16]
  __shared__ int   cidx[16];
  int tid = threadIdx.x;
  if (tid < 16) cidx[tid] = chars[tid];
  __syncthreads();
  for (int e = tid; e < 1600; e += 128) {
    int i = e >> 4, p = e & 15;
    xl[e] = char_emb[cidx[p] * 100 + i];
  }
  __syncthreads();
  if (tid < 100) {
    int o = tid;
    float acc[16];
#pragma unroll
    for (int p = 0; p < 16; ++p) acc[p] = 0.f;
    const float* wo = conv_w + o * 500;
    for (int i = 0; i < 100; ++i) {
      const float* xi = xl + i * 16;
#pragma unroll
      for (int k = 0; k < 5; ++k) {
        float w = wo[i * 5 + k];
#pragma unroll
        for (int p = 0; p < 16; ++p) {
          int src = p + k - 2;
          if (src >= 0 && src < 16) acc[p] += w * xi[src];
        }
      }
    }
    float m = acc[0];
#pragma unroll
    for (int p = 1; p < 16; ++p) m = fmaxf(m, acc[p]);
    x_all[(size_t)n * 356 + o] = m + conv_b[o];
  }
  for (int j = tid; j < 256; j += 128)
    x_all[(size_t)n * 356 + 100 + j] = elmo[j];
}

// ---------------------------------------------------------------------------
// fp32 GEMM:  C[M,N] = A[M,K] @ B[N,K]^T + bias[N]
// 128x128 tile, BK=8, block=256, 8x8 per thread, float4 global + b128 LDS.
// Caller guarantees M % 128 == 0 and K % 4 == 0.
// ---------------------------------------------------------------------------
__global__ __launch_bounds__(256) void gemm128(
    const float* __restrict__ A, const float* __restrict__ B,
    const float* __restrict__ bias, float* __restrict__ C,
    int M, int N, int K)
{
  __shared__ float As[8][132];
  __shared__ float Bs[8][132];
  int tid = threadIdx.x;
  int bm = blockIdx.y * 128, bn = blockIdx.x * 128;
  int r = tid >> 1;            // 0..127
  int c = (tid & 1) * 4;       // 0 or 4
  const float* Arow = A + (size_t)(bm + r) * K;
  const float* Brow = B + (size_t)(bn + r) * K;
  bool brow_ok = (bn + r) < N;
  int m0 = (tid >> 4) * 8;     // 0..120
  int n0 = (tid & 15) * 8;     // 0..120
  float acc[8][8];
#pragma unroll
  for (int i = 0; i < 8; ++i)
#pragma unroll
    for (int j = 0; j < 8; ++j) acc[i][j] = 0.f;

  for (int k0 = 0; k0 < K; k0 += 8) {
    int gk = k0 + c;
    bool kv = gk < K;   // K%4==0: float4 all-or-none
    float4 av = kv ? *(const float4*)(Arow + gk) : float4{0, 0, 0, 0};
    float4 bv = (kv && brow_ok) ? *(const float4*)(Brow + gk) : float4{0, 0, 0, 0};
    __syncthreads();
    As[c + 0][r] = av.x; As[c + 1][r] = av.y; As[c + 2][r] = av.z; As[c + 3][r] = av.w;
    Bs[c + 0][r] = bv.x; Bs[c + 1][r] = bv.y; Bs[c + 2][r] = bv.z; Bs[c + 3][r] = bv.w;
    __syncthreads();
#pragma unroll
    for (int kk = 0; kk < 8; ++kk) {
      float4 a0 = *(const float4*)&As[kk][m0];
      float4 a1 = *(const float4*)&As[kk][m0 + 4];
      float4 b0 = *(const float4*)&Bs[kk][n0];
      float4 b1 = *(const float4*)&Bs[kk][n0 + 4];
      float a[8] = {a0.x, a0.y, a0.z, a0.w, a1.x, a1.y, a1.z, a1.w};
      float b[8] = {b0.x, b0.y, b0.z, b0.w, b1.x, b1.y, b1.z, b1.w};
#pragma unroll
      for (int i = 0; i < 8; ++i)
#pragma unroll
        for (int j = 0; j < 8; ++j) acc[i][j] += a[i] * b[j];
    }
  }
#pragma unroll
  for (int i = 0; i < 8; ++i) {
    int gm = bm + m0 + i;
    float* Cr = C + (size_t)gm * N;
#pragma unroll
    for (int j = 0; j < 8; ++j) {
      int gn = bn + n0 + j;
      if (gn < N) Cr[gn] = acc[i][j] + (bias ? bias[gn] : 0.f);
    }
  }
}

// ---------------------------------------------------------------------------
// highway combine
// ---------------------------------------------------------------------------
__global__ void highway_combine(float* __restrict__ x, const float* __restrict__ g,
                                const float* __restrict__ p, int total)
{
  int i = blockIdx.x * blockDim.x + threadIdx.x;
  if (i < total) {
    float gg = sigm(g[i]);
    float pp = fmaxf(p[i], 0.f);
    x[i] = gg * pp + (1.f - gg) * x[i];
  }
}

// ---------------------------------------------------------------------------
// persistent BiLSTM scan, v3: XCD-homed exchange.
// Launch 256 blocks x 1024 thr (dir = blockIdx&1, 128 candidates/dir).
// Election: each block reads HW_REG_XCC_ID, bumps arrivals[dir][xcd] (agent
// atomics), waits until all 128 of its dir reported, picks home=argmax.
// 8 winners/dir (all on home XCD) run the scan; losers exit.
// Exchange: producer stores epoch-packed u64 with sc0|sc1 (write-through to
// coherence point — correct for ANY placement); consumers poll with sc0
// loads that hit the home XCD's shared L2, escalating to sc0|sc1 after 64
// stale polls (so even a broken election only costs speed, never deadlock).
// ---------------------------------------------------------------------------
#define KBLK 128   // candidate blocks per dir
#define NWGS 8     // winners per dir
#define SLICE 45   // 8*45 = 360 >= 356
#define ZROWS 180  // 4*SLICE

__global__ __launch_bounds__(1024, 1) void lstm_scan_kernel(
    const float* __restrict__ xw, const float* __restrict__ whh,
    const float* __restrict__ h0, float* __restrict__ out,
    int row0, int N, unsigned long long* exbuf, unsigned* ctrl)
{
  const int tid = threadIdx.x;
  const int dir = blockIdx.x & 1;

  // ---- election ----
  __shared__ unsigned s_rank, s_home;
  unsigned xcc;
  asm volatile("s_getreg_b32 %0, hwreg(HW_REG_XCC_ID)" : "=s"(xcc));
  xcc &= 15;
  unsigned* arr = ctrl + dir * 16;   // one 64B line per dir
  if (tid == 0) {
    s_rank = __hip_atomic_fetch_add(&arr[xcc], 1u, __ATOMIC_RELAXED,
                                    __HIP_MEMORY_SCOPE_AGENT);
    // wait for all KBLK blocks of this dir to report
    unsigned cnt[16];
    for (;;) {
      unsigned s = 0;
      for (int x = 0; x < 16; ++x) {
        cnt[x] = __hip_atomic_load(&arr[x], __ATOMIC_RELAXED, __HIP_MEMORY_SCOPE_AGENT);
        s += cnt[x];
      }
      if (s == KBLK) break;
      __builtin_amdgcn_s_sleep(1);
    }
    unsigned best = 0, bestc = cnt[0];
    for (int x = 1; x < 16; ++x)
      if (cnt[x] > bestc) { bestc = cnt[x]; best = (unsigned)x; }
    s_home = best;   // bestc >= ceil(128/16) = 8
  }
  __syncthreads();
  if (xcc != s_home || s_rank >= NWGS) return;
  const int wg = (int)s_rank;        // 0..7

  // ---- scan setup ----
  const int lane = tid & 63;
  const int wv   = tid >> 6;         // 0..15
  const int j0   = wg * SLICE;
  const float* whh_d = whh + (size_t)dir * 1424 * 356;
  const float* h0_d  = h0 + dir * 356;
  const int xcol0 = dir * 1424;
  const int ocol0 = dir * 356;
  unsigned long long* exd = exbuf + dir * 712;   // [parity][356]

  __shared__ float h_lds[384];
  __shared__ float z_lds[ZROWS];

  // z-duty: tid < 180 handles one (gate, jj) of z/xw
  const bool zduty = (tid < ZROWS);
  bool zvalid = false;
  size_t xcol = 0;
  if (zduty) {
    int zgate = tid / SLICE, zjj = tid % SLICE, zj = j0 + zjj;
    zvalid = (zj < 356);
    xcol = (size_t)(xcol0 + zgate * 356 + zj);
  }

  // Whh slice -> VGPRs: wave wv handles rows rr = wv*12 + q (q<12, rr<180)
  float wreg[12][6];
#pragma unroll
  for (int q = 0; q < 12; ++q) {
    int rr = wv * 12 + q;
    bool rv = (rr < ZROWS);
    int gate = rv ? (rr / SLICE) : 0, jj = rv ? (rr % SLICE) : 0;
    int j = j0 + jj;
    bool v = rv && (j < 356);
    int row_g = gate * 356 + j;
#pragma unroll
    for (int ii = 0; ii < 6; ++ii) {
      int k = lane + ii * 64;
      wreg[q][ii] = (v && k < 356) ? whh_d[(size_t)row_g * 356 + k] : 0.f;
    }
  }

  for (int k = tid; k < 384; k += 1024) h_lds[k] = (k < 356) ? h0_d[k] : 0.f;
  float c_reg = 0.f;
  if (tid < SLICE) { int j = j0 + tid; if (j < 356) c_reg = h0_d[j]; }

  float xw_cur = 0.f;
  {
    int row = dir ? (N - 1) : 0;
    if (zvalid) xw_cur = xw[(size_t)(row0 + row) * 2848 + xcol];
  }
  __syncthreads();

  for (int t = 0; t < N; ++t) {
    int row = dir ? (N - 1 - t) : t;
    size_t grow = (size_t)(row0 + row);

    // A: z init + prefetch next xw
    if (zduty) z_lds[tid] = zvalid ? xw_cur : 0.f;
    float xw_nx = 0.f;
    {
      int tn = (t + 1 < N) ? (t + 1) : (N - 1);
      int rown = dir ? (N - 1 - tn) : tn;
      if (zvalid) xw_nx = xw[(size_t)(row0 + rown) * 2848 + xcol];
    }
    __syncthreads();

    // B: z[rr] += Whh_row . h  (h hoisted to regs, reused across 12 rows)
    {
      float hv[6];
#pragma unroll
      for (int ii = 0; ii < 6; ++ii) hv[ii] = h_lds[lane + ii * 64];
#pragma unroll
      for (int q = 0; q < 12; ++q) {
        float s = 0.f;
#pragma unroll
        for (int ii = 0; ii < 6; ++ii) s += wreg[q][ii] * hv[ii];
        s = waveSum(s);
        int rr = wv * 12 + q;
        if (lane == 0 && rr < ZROWS) z_lds[rr] += s;
      }
    }
    __syncthreads();

    // C: gates + publish
    if (tid < SLICE) {
      int j = j0 + tid;
      if (j < 356) {
        float zi = z_lds[tid], zf = z_lds[SLICE + tid];
        float zg = z_lds[2 * SLICE + tid], zo = z_lds[3 * SLICE + tid];
        float cc = sigm(zf) * c_reg + sigm(zi) * tanhf(zg);
        float h = sigm(zo) * tanhf(cc);
        c_reg = cc;
        out[grow * 712 + ocol0 + j] = h;
        unsigned long long pk =
            ((unsigned long long)(unsigned)(t + 1) << 32) |
            (unsigned long long)__float_as_uint(h);
        st_thru_u64(&exd[(size_t)(t & 1) * 356 + j], pk);
      }
    }

    // D: poll own word (L2 fast path, coherence-point escalation)
    if (tid < 356) {
      unsigned long long* p = &exd[(size_t)(t & 1) * 356 + tid];
      unsigned ep = (unsigned)(t + 1);
      unsigned long long v;
      int tries = 0;
      for (;;) {
        v = (tries < 64) ? ld_sc0_u64(p) : ld_sc01_u64(p);
        if ((unsigned)(v >> 32) == ep) break;
        ++tries;
      }
      h_lds[tid] = __uint_as_float((unsigned)v);
    }
    __syncthreads();

    xw_cur = xw_nx;
  }
}

// ---------------------------------------------------------------------------
// attention: s2[j] = Q[j] . w_q
// ---------------------------------------------------------------------------
__global__ __launch_bounds__(64) void qdot_kernel(
    const float* __restrict__ Q, const float* __restrict__ sim_w, float* __restrict__ s2)
{
  int j = blockIdx.x;
  int lane = threadIdx.x;
  const float* q  = Q + (size_t)j * 712;
  const float* wq = sim_w + 712;
  float s = 0.f;
  for (int k = lane; k < 712; k += 64) s += q[k] * wq[k];
  s = waveSum(s);
  if (lane == 0) s2[j] = s;
}

// ---------------------------------------------------------------------------
// per-context-row attention + qac[0,2136)
// ---------------------------------------------------------------------------
__global__ __launch_bounds__(256) void attn_row_kernel(
    const float* __restrict__ CQ, const float* __restrict__ sim_w,
    const float* __restrict__ s2, float* __restrict__ rowm, float* __restrict__ qac)
{
  int i = blockIdx.x;   // 0..4095
  int tid = threadIdx.x;
  const float* Q = CQ + (size_t)4096 * 712;
  __shared__ float crow[712], cw[712], prow[128], red[256];
  const float* ci = CQ + (size_t)i * 712;

  float s1p = 0.f;
  for (int k = tid; k < 712; k += 256) {
    float v = ci[k];
    crow[k] = v;
    cw[k] = v * sim_w[1424 + k];
    s1p += v * sim_w[k];
  }
  red[tid] = s1p;
  __syncthreads();
  for (int s = 128; s > 0; s >>= 1) { if (tid < s) red[tid] += red[tid + s]; __syncthreads(); }
  float s1 = red[0];

  int lane = tid & 63, wv = tid >> 6;
  for (int j = wv; j < 128; j += 4) {
    const float* qj = Q + (size_t)j * 712;
    float s = 0.f;
    for (int k = lane; k < 712; k += 64) s += cw[k] * qj[k];
    s = waveSum(s);
    if (lane == 0) prow[j] = s1 + s2[j] + s;
  }
  __syncthreads();

  float v = (tid < 128) ? prow[tid] : -1e30f;
  red[tid] = v;
  __syncthreads();
  for (int s = 128; s > 0; s >>= 1) { if (tid < s) red[tid] = fmaxf(red[tid], red[tid + s]); __syncthreads(); }
  float m = red[0];
  __syncthreads();
  float e = (tid < 128) ? __expf(prow[tid] - m) : 0.f;
  red[tid] = e;
  __syncthreads();
  for (int s = 128; s > 0; s >>= 1) { if (tid < s) red[tid] += red[tid + s]; __syncthreads(); }
  float denom = red[0];
  if (tid < 128) prow[tid] = e / denom;
  if (tid == 0) rowm[i] = m;
  __syncthreads();

  size_t qb = (size_t)i * 2848;
  for (int k = tid; k < 712; k += 256) {
    float acc = 0.f;
    for (int j = 0; j < 128; ++j) acc += prow[j] * Q[(size_t)j * 712 + k];
    float cv = crow[k];
    qac[qb + k]        = cv;
    qac[qb + 712 + k]  = acc;
    qac[qb + 1424 + k] = cv * acc;
  }
}

// ---------------------------------------------------------------------------
// softmax over a length-4096 vector (single block)
// ---------------------------------------------------------------------------
__global__ __launch_bounds__(256) void softmax_4096(const float* __restrict__ in,
                                                    float* __restrict__ out)
{
  __shared__ float red[256];
  int tid = threadIdx.x;
  float m = -1e30f;
  for (int i = tid; i < 4096; i += 256) m = fmaxf(m, in[i]);
  red[tid] = m;
  __syncthreads();
  for (int s = 128; s > 0; s >>= 1) { if (tid < s) red[tid] = fmaxf(red[tid], red[tid + s]); __syncthreads(); }
  m = red[0];
  __syncthreads();
  float sum = 0.f;
  for (int i = tid; i < 4096; i += 256) sum += __expf(in[i] - m);
  red[tid] = sum;
  __syncthreads();
  for (int s = 128; s > 0; s >>= 1) { if (tid < s) red[tid] += red[tid + s]; __syncthreads(); }
  float denom = red[0];
  for (int i = tid; i < 4096; i += 256) out[i] = __expf(in[i] - m) / denom;
}

// ---------------------------------------------------------------------------
// q2c[k] = sum_i a[i]*C[i,k]
// ---------------------------------------------------------------------------
__global__ __launch_bounds__(256) void q2c_kernel(
    const float* __restrict__ CQ, const float* __restrict__ rowa, float* __restrict__ q2c)
{
  int k = blockIdx.x * 256 + threadIdx.x;
  if (k < 712) {
    float acc = 0.f;
    for (int i = 0; i < 4096; ++i) acc += rowa[i] * CQ[(size_t)i * 712 + k];
    q2c[k] = acc;
  }
}

__global__ __launch_bounds__(256) void qac_finish_kernel(
    const float* __restrict__ CQ, const float* __restrict__ q2c, float* __restrict__ qac)
{
  int i = blockIdx.x;
  int tid = threadIdx.x;
  for (int k = tid; k < 712; k += 256)
    qac[(size_t)i * 2848 + 2136 + k] = CQ[(size_t)i * 712 + k] * q2c[k];
}

__global__ __launch_bounds__(256) void logits_kernel(
    const float* __restrict__ qac, const float* __restrict__ Mx,
    const float* __restrict__ w, float* __restrict__ logits)
{
  int i = blockIdx.x, tid = threadIdx.x;
  __shared__ float red[256];
  float s = 0.f;
  const float* qr = qac + (size_t)i * 2848;
  for (int k = tid; k < 2848; k += 256) s += qr[k] * w[k];
  const float* mr = Mx + (size_t)i * 712;
  for (int k = tid; k < 712; k += 256) s += mr[k] * w[2848 + k];
  red[tid] = s;
  __syncthreads();
  for (int st = 128; st > 0; st >>= 1) { if (tid < st) red[tid] += red[tid + st]; __syncthreads(); }
  if (tid == 0) logits[i] = red[0];
}

// ---------------------------------------------------------------------------
// host side
// ---------------------------------------------------------------------------
extern "C" void kernel_launch(void* const* d_in, const int* in_sizes, int n_in,
                              void* d_out, int out_size, void* d_ws, size_t ws_size,
                              hipStream_t stream)
{
  const int*   chars_ctx = (const int*)d_in[0];
  const int*   chars_qry = (const int*)d_in[1];
  const float* elmo_ctx  = (const float*)d_in[2];
  const float* elmo_qry  = (const float*)d_in[3];
  const float* char_emb  = (const float*)d_in[4];
  const float* conv_w    = (const float*)d_in[5];
  const float* conv_b    = (const float*)d_in[6];
  const float* hw_plain_w = (const float*)d_in[7];
  const float* hw_plain_b = (const float*)d_in[8];
  const float* hw_gate_w  = (const float*)d_in[9];
  const float* hw_gate_b  = (const float*)d_in[10];
  const float* ctx_Wih   = (const float*)d_in[11];
  const float* ctx_Whh   = (const float*)d_in[12];
  const float* ctx_b     = (const float*)d_in[13];
  const float* sim_w     = (const float*)d_in[14];
  const float* mod1_Wih  = (const float*)d_in[15];
  const float* mod1_Whh  = (const float*)d_in[16];
  const float* mod1_b    = (const float*)d_in[17];
  const float* mod2_Wih  = (const float*)d_in[18];
  const float* mod2_Whh  = (const float*)d_in[19];
  const float* mod2_b    = (const float*)d_in[20];
  const float* pos_Wih   = (const float*)d_in[21];
  const float* pos_Whh   = (const float*)d_in[22];
  const float* pos_b     = (const float*)d_in[23];
  const float* pos1_w    = (const float*)d_in[24];
  const float* pos2_w    = (const float*)d_in[25];
  const float* h0_ctx_c  = (const float*)d_in[26];
  const float* h0_ctx_q  = (const float*)d_in[27];
  const float* h0_mod    = (const float*)d_in[28];
  const float* h0_pos    = (const float*)d_in[29];
  float* outp = (float*)d_out;

  float* ws = (float*)d_ws;
  size_t off = 0;
  auto alloc = [&](size_t n) { float* p = ws + off; off += n; return p; };
  float* x_all  = alloc(4224ull * 356);
  float* gbuf   = alloc(4224ull * 356);
  float* pbuf   = alloc(4224ull * 356);
  float* xw_all = alloc(4224ull * 2848);
  float* CQ     = alloc(4224ull * 712);
  float* M1     = alloc(4096ull * 712);
  float* Mm     = alloc(4096ull * 712);
  float* M2     = alloc(4096ull * 712);
  float* qac    = alloc(4096ull * 2848);
  float* s2v    = alloc(128);
  float* rowm   = alloc(4096);
  float* rowa   = alloc(4096);
  float* q2cv   = alloc(1024);
  float* logits = alloc(8192);
  off = (off + 3) & ~(size_t)3;                    // 16B align
  unsigned long long* exbuf = (unsigned long long*)(ws + off);
  // 5 scans x [2 dirs][2 parity][356] u64; 0xAA poison != any epoch.
  off += 5ull * 1424 * 2;
  unsigned* ctrl = (unsigned*)(ws + off);          // 5 scans x 2 dirs x 16
  off += 160;

  auto cdiv = [](int a, int b) { return (a + b - 1) / b; };

  // zero election counters
  hipMemsetAsync(ctrl, 0, 160 * sizeof(unsigned), stream);

  // 1) char CNN + elmo concat
  cnn_embed_kernel<<<4224, 128, 0, stream>>>(chars_ctx, chars_qry, elmo_ctx, elmo_qry,
                                             char_emb, conv_w, conv_b, x_all);

  // 2) highway x2   (M=4224 %128==0, K=356 %4==0)
  for (int l = 0; l < 2; ++l) {
    gemm128<<<dim3(cdiv(356, 128), 33), 256, 0, stream>>>(
        x_all, hw_gate_w + (size_t)l * 356 * 356, hw_gate_b + l * 356, gbuf, 4224, 356, 356);
    gemm128<<<dim3(cdiv(356, 128), 33), 256, 0, stream>>>(
        x_all, hw_plain_w + (size_t)l * 356 * 356, hw_plain_b + l * 356, pbuf, 4224, 356, 356);
    highway_combine<<<cdiv(4224 * 356, 256), 256, 0, stream>>>(x_all, gbuf, pbuf, 4224 * 356);
  }

  // 3) ctx BiLSTM
  gemm128<<<dim3(cdiv(2848, 128), 33), 256, 0, stream>>>(
      x_all, ctx_Wih, ctx_b, xw_all, 4224, 2848, 356);
  lstm_scan_kernel<<<2 * KBLK, 1024, 0, stream>>>(xw_all, ctx_Whh, h0_ctx_c, CQ, 0, 4096,
                                                  exbuf + 0ull * 1424, ctrl + 0);
  lstm_scan_kernel<<<2 * KBLK, 1024, 0, stream>>>(xw_all, ctx_Whh, h0_ctx_q, CQ, 4096, 128,
                                                  exbuf + 1ull * 1424, ctrl + 32);

  // 4) attention
  qdot_kernel<<<128, 64, 0, stream>>>(CQ + 4096ull * 712, sim_w, s2v);
  attn_row_kernel<<<4096, 256, 0, stream>>>(CQ, sim_w, s2v, rowm, qac);
  softmax_4096<<<1, 256, 0, stream>>>(rowm, rowa);
  q2c_kernel<<<cdiv(712, 256), 256, 0, stream>>>(CQ, rowa, q2cv);
  qac_finish_kernel<<<4096, 256, 0, stream>>>(CQ, q2cv, qac);

  // 5) mod1 BiLSTM (input 2848)
  gemm128<<<dim3(cdiv(2848, 128), 32), 256, 0, stream>>>(
      qac, mod1_Wih, mod1_b, xw_all, 4096, 2848, 2848);
  lstm_scan_kernel<<<2 * KBLK, 1024, 0, stream>>>(xw_all, mod1_Whh, h0_mod, M1, 0, 4096,
                                                  exbuf + 2ull * 1424, ctrl + 64);

  // 6) mod2 BiLSTM (input 712)
  gemm128<<<dim3(cdiv(2848, 128), 32), 256, 0, stream>>>(
      M1, mod2_Wih, mod2_b, xw_all, 4096, 2848, 712);
  lstm_scan_kernel<<<2 * KBLK, 1024, 0, stream>>>(xw_all, mod2_Whh, h0_mod + 712, Mm, 0, 4096,
                                                  exbuf + 3ull * 1424, ctrl + 96);

  // 7) pos1
  logits_kernel<<<4096, 256, 0, stream>>>(qac, Mm, pos1_w, logits);
  softmax_4096<<<1, 256, 0, stream>>>(logits, outp);

  // 8) pos BiLSTM then pos2
  gemm128<<<dim3(cdiv(2848, 128), 32), 256, 0, stream>>>(
      Mm, pos_Wih, pos_b, xw_all, 4096, 2848, 712);
  lstm_scan_kernel<<<2 * KBLK, 1024, 0, stream>>>(xw_all, pos_Whh, h0_pos, M2, 0, 4096,
                                                  exbuf + 4ull * 1424, ctrl + 128);
  logits_kernel<<<4096, 256, 0, stream>>>(qac, M2, pos2_w, logits + 4096);
  softmax_4096<<<1, 256, 0, stream>>>(logits + 4096, outp + 4096);

  (void)in_sizes; (void)n_in; (void)out_size; (void)ws_size;
}

// Round 4
// 94478.094 us; speedup vs baseline: 2.0312x; 2.0312x over previous
//
#include <hip/hip_runtime.h>
#include <math.h>

// ---------------------------------------------------------------------------
// helpers
// ---------------------------------------------------------------------------
__device__ __forceinline__ float sigm(float x) { return 1.0f / (1.0f + __expf(-x)); }

__device__ __forceinline__ float waveSum(float v) {
#pragma unroll
  for (int off = 32; off > 0; off >>= 1) v += __shfl_xor(v, off);
  return v;
}

// ---------------------------------------------------------------------------
// char CNN + elmo concat  -> x_all (4224 x 356)
// ---------------------------------------------------------------------------
__global__ __launch_bounds__(128) void cnn_embed_kernel(
    const int* __restrict__ chars_ctx, const int* __restrict__ chars_qry,
    const float* __restrict__ elmo_ctx, const float* __restrict__ elmo_qry,
    const float* __restrict__ char_emb, const float* __restrict__ conv_w,
    const float* __restrict__ conv_b, float* __restrict__ x_all)
{
  int n = blockIdx.x;
  const int*   chars = (n < 4096) ? (chars_ctx + n * 16) : (chars_qry + (n - 4096) * 16);
  const float* elmo  = (n < 4096) ? (elmo_ctx + (size_t)n * 256)
                                  : (elmo_qry + (size_t)(n - 4096) * 256);
  __shared__ float xl[1600];   // [emb_dim=100][pos=16]
  __shared__ int   cidx[16];
  int tid = threadIdx.x;
  if (tid < 16) cidx[tid] = chars[tid];
  __syncthreads();
  for (int e = tid; e < 1600; e += 128) {
    int i = e >> 4, p = e & 15;
    xl[e] = char_emb[cidx[p] * 100 + i];
  }
  __syncthreads();
  if (tid < 100) {
    int o = tid;
    float acc[16];
#pragma unroll
    for (int p = 0; p < 16; ++p) acc[p] = 0.f;
    const float* wo = conv_w + o * 500;
    for (int i = 0; i < 100; ++i) {
      const float* xi = xl + i * 16;
#pragma unroll
      for (int k = 0; k < 5; ++k) {
        float w = wo[i * 5 + k];
#pragma unroll
        for (int p = 0; p < 16; ++p) {
          int src = p + k - 2;
          if (src >= 0 && src < 16) acc[p] += w * xi[src];
        }
      }
    }
    float m = acc[0];
#pragma unroll
    for (int p = 1; p < 16; ++p) m = fmaxf(m, acc[p]);
    x_all[(size_t)n * 356 + o] = m + conv_b[o];
  }
  for (int j = tid; j < 256; j += 128)
    x_all[(size_t)n * 356 + 100 + j] = elmo[j];
}

// ---------------------------------------------------------------------------
// fp32 GEMM:  C[M,N] = A[M,K] @ B[N,K]^T + bias[N]
// 128x128 tile, BK=8, block=256, 8x8 per thread, float4 global + b128 LDS.
// Caller guarantees M % 128 == 0 and K % 4 == 0.
// ---------------------------------------------------------------------------
__global__ __launch_bounds__(256) void gemm128(
    const float* __restrict__ A, const float* __restrict__ B,
    const float* __restrict__ bias, float* __restrict__ C,
    int M, int N, int K)
{
  __shared__ float As[8][132];
  __shared__ float Bs[8][132];
  int tid = threadIdx.x;
  int bm = blockIdx.y * 128, bn = blockIdx.x * 128;
  int r = tid >> 1;            // 0..127
  int c = (tid & 1) * 4;       // 0 or 4
  const float* Arow = A + (size_t)(bm + r) * K;
  const float* Brow = B + (size_t)(bn + r) * K;
  bool brow_ok = (bn + r) < N;
  int m0 = (tid >> 4) * 8;     // 0..120
  int n0 = (tid & 15) * 8;     // 0..120
  float acc[8][8];
#pragma unroll
  for (int i = 0; i < 8; ++i)
#pragma unroll
    for (int j = 0; j < 8; ++j) acc[i][j] = 0.f;

  for (int k0 = 0; k0 < K; k0 += 8) {
    int gk = k0 + c;
    bool kv = gk < K;   // K%4==0: float4 all-or-none
    float4 av = kv ? *(const float4*)(Arow + gk) : float4{0, 0, 0, 0};
    float4 bv = (kv && brow_ok) ? *(const float4*)(Brow + gk) : float4{0, 0, 0, 0};
    __syncthreads();
    As[c + 0][r] = av.x; As[c + 1][r] = av.y; As[c + 2][r] = av.z; As[c + 3][r] = av.w;
    Bs[c + 0][r] = bv.x; Bs[c + 1][r] = bv.y; Bs[c + 2][r] = bv.z; Bs[c + 3][r] = bv.w;
    __syncthreads();
#pragma unroll
    for (int kk = 0; kk < 8; ++kk) {
      float4 a0 = *(const float4*)&As[kk][m0];
      float4 a1 = *(const float4*)&As[kk][m0 + 4];
      float4 b0 = *(const float4*)&Bs[kk][n0];
      float4 b1 = *(const float4*)&Bs[kk][n0 + 4];
      float a[8] = {a0.x, a0.y, a0.z, a0.w, a1.x, a1.y, a1.z, a1.w};
      float b[8] = {b0.x, b0.y, b0.z, b0.w, b1.x, b1.y, b1.z, b1.w};
#pragma unroll
      for (int i = 0; i < 8; ++i)
#pragma unroll
        for (int j = 0; j < 8; ++j) acc[i][j] += a[i] * b[j];
    }
  }
#pragma unroll
  for (int i = 0; i < 8; ++i) {
    int gm = bm + m0 + i;
    float* Cr = C + (size_t)gm * N;
#pragma unroll
    for (int j = 0; j < 8; ++j) {
      int gn = bn + n0 + j;
      if (gn < N) Cr[gn] = acc[i][j] + (bias ? bias[gn] : 0.f);
    }
  }
}

// ---------------------------------------------------------------------------
// highway combine
// ---------------------------------------------------------------------------
__global__ void highway_combine(float* __restrict__ x, const float* __restrict__ g,
                                const float* __restrict__ p, int total)
{
  int i = blockIdx.x * blockDim.x + threadIdx.x;
  if (i < total) {
    float gg = sigm(g[i]);
    float pp = fmaxf(p[i], 0.f);
    x[i] = gg * pp + (1.f - gg) * x[i];
  }
}

// ---------------------------------------------------------------------------
// persistent BiLSTM scan, v4: flag-gated epoch exchange.
// grid = 16 blocks x 1024 thr (dir = blockIdx&1, wg = blockIdx>>1, 8 WGs/dir).
// Each WG owns SLICE=45 hidden units (180 Whh rows) in VGPRs.
// Per step: producers (lanes 0..44 of wave 0) store epoch-packed u64 data
// words (relaxed agent atomics), s_waitcnt vmcnt(0), lane 0 stores a per-WG
// epoch FLAG. Consumers poll ONLY the 8 flags (8 lanes of wave 0, one
// coalesced request per poll) -> __syncthreads releases all waves to load
// the foreign h words in one parallel burst. Data words self-verify their
// epoch (covers any store->flag reordering). Double-buffered by parity;
// the flag handshake makes slot reuse provably race-free.
// ---------------------------------------------------------------------------
#define NWGS 8
#define SLICE 45   // 8*45 = 360 >= 356
#define ZROWS 180  // 4*SLICE

__global__ __launch_bounds__(1024, 1) void lstm_scan_kernel(
    const float* __restrict__ xw, const float* __restrict__ whh,
    const float* __restrict__ h0, float* __restrict__ out,
    int row0, int N, unsigned long long* exbuf)
{
  const int tid  = threadIdx.x;
  const int dir  = blockIdx.x & 1;
  const int wg   = blockIdx.x >> 1;
  const int lane = tid & 63;
  const int wv   = tid >> 6;         // 0..15
  const int j0   = wg * SLICE;
  const float* whh_d = whh + (size_t)dir * 1424 * 356;
  const float* h0_d  = h0 + dir * 356;
  const int xcol0 = dir * 1424;
  const int ocol0 = dir * 356;
  unsigned long long* exd = exbuf + (size_t)dir * 728;   // data  [2][356]
  unsigned long long* exf = exd + 712;                   // flags [2][8]

  __shared__ float h_lds[384];
  __shared__ float z_lds[ZROWS];

  // z-duty: tid < 180 handles one (gate, jj) of z/xw
  bool zvalid = false;
  size_t xcol = 0;
  if (tid < ZROWS) {
    int zgate = tid / SLICE, zjj = tid % SLICE, zj = j0 + zjj;
    zvalid = (zj < 356);
    xcol = (size_t)(xcol0 + zgate * 356 + zj);
  }

  // Whh slice -> VGPRs: wave wv handles rows rr = wv*12 + q (q<12, rr<180)
  float wreg[12][6];
#pragma unroll
  for (int q = 0; q < 12; ++q) {
    int rr = wv * 12 + q;
    bool rv = (rr < ZROWS);
    int gate = rv ? (rr / SLICE) : 0, jj = rv ? (rr % SLICE) : 0;
    int j = j0 + jj;
    bool v = rv && (j < 356);
    int row_g = gate * 356 + j;
#pragma unroll
    for (int ii = 0; ii < 6; ++ii) {
      int k = lane + ii * 64;
      wreg[q][ii] = (v && k < 356) ? whh_d[(size_t)row_g * 356 + k] : 0.f;
    }
  }

  for (int k = tid; k < 384; k += 1024) h_lds[k] = (k < 356) ? h0_d[k] : 0.f;
  float c_reg = 0.f;
  if (tid < SLICE) { int j = j0 + tid; if (j < 356) c_reg = h0_d[j]; }

  float xw_cur = 0.f;
  {
    int row = dir ? (N - 1) : 0;
    if (zvalid) xw_cur = xw[(size_t)(row0 + row) * 2848 + xcol];
  }
  __syncthreads();

  for (int t = 0; t < N; ++t) {
    int row = dir ? (N - 1 - t) : t;
    size_t grow = (size_t)(row0 + row);
    int par = t & 1;
    unsigned long long tgt = (unsigned long long)(unsigned)(t + 1);

    // A: z init from prefetched xw; issue prefetch for t+1
    if (tid < ZROWS) z_lds[tid] = zvalid ? xw_cur : 0.f;
    float xw_nx = 0.f;
    {
      int tn = (t + 1 < N) ? (t + 1) : (N - 1);
      int rown = dir ? (N - 1 - tn) : tn;
      if (zvalid) xw_nx = xw[(size_t)(row0 + rown) * 2848 + xcol];
    }
    __syncthreads();

    // B: z[rr] += Whh_row . h
    {
      float hv[6];
#pragma unroll
      for (int ii = 0; ii < 6; ++ii) hv[ii] = h_lds[lane + ii * 64];
#pragma unroll
      for (int q = 0; q < 12; ++q) {
        float s = 0.f;
#pragma unroll
        for (int ii = 0; ii < 6; ++ii) s += wreg[q][ii] * hv[ii];
        s = waveSum(s);
        int rr = wv * 12 + q;
        if (lane == 0 && rr < ZROWS) z_lds[rr] += s;
      }
    }
    __syncthreads();

    // C: gates + publish (producers are lanes 0..44 of wave 0)
    if (tid < SLICE) {
      int j = j0 + tid;
      if (j < 356) {
        float zi = z_lds[tid], zf = z_lds[SLICE + tid];
        float zg = z_lds[2 * SLICE + tid], zo = z_lds[3 * SLICE + tid];
        float cc = sigm(zf) * c_reg + sigm(zi) * tanhf(zg);
        float h = sigm(zo) * tanhf(cc);
        c_reg = cc;
        out[grow * 712 + ocol0 + j] = h;
        h_lds[j] = h;   // own slice fresh locally
        unsigned long long pk = (tgt << 32) |
            (unsigned long long)__float_as_uint(h);
        __hip_atomic_store(&exd[(size_t)par * 356 + j], pk,
                           __ATOMIC_RELAXED, __HIP_MEMORY_SCOPE_AGENT);
      }
    }

    // wave 0: drain data stores, raise flag, then poll all 8 flags
    if (wv == 0) {
      asm volatile("s_waitcnt vmcnt(0)" ::: "memory");
      if (tid == 0)
        __hip_atomic_store(&exf[(size_t)par * 8 + wg], tgt,
                           __ATOMIC_RELAXED, __HIP_MEMORY_SCOPE_AGENT);
      for (;;) {
        unsigned long long v = tgt;
        if (lane < NWGS)
          v = __hip_atomic_load(&exf[(size_t)par * 8 + lane],
                                __ATOMIC_RELAXED, __HIP_MEMORY_SCOPE_AGENT);
        if (__ballot(v != tgt) == 0ull) break;
      }
    }
    __syncthreads();   // releases all waves: every WG has published

    // D: fetch foreign h words (self-verifying epoch)
    if (tid < 356 && (tid < j0 || tid >= j0 + SLICE)) {
      unsigned long long* p = &exd[(size_t)par * 356 + tid];
      unsigned long long v;
      do {
        v = __hip_atomic_load(p, __ATOMIC_RELAXED, __HIP_MEMORY_SCOPE_AGENT);
      } while ((unsigned)(v >> 32) != (unsigned)tgt);
      h_lds[tid] = __uint_as_float((unsigned)v);
    }
    __syncthreads();

    xw_cur = xw_nx;
  }
}

// ---------------------------------------------------------------------------
// attention: s2[j] = Q[j] . w_q
// ---------------------------------------------------------------------------
__global__ __launch_bounds__(64) void qdot_kernel(
    const float* __restrict__ Q, const float* __restrict__ sim_w, float* __restrict__ s2)
{
  int j = blockIdx.x;
  int lane = threadIdx.x;
  const float* q  = Q + (size_t)j * 712;
  const float* wq = sim_w + 712;
  float s = 0.f;
  for (int k = lane; k < 712; k += 64) s += q[k] * wq[k];
  s = waveSum(s);
  if (lane == 0) s2[j] = s;
}

// ---------------------------------------------------------------------------
// per-context-row attention + qac[0,2136)
// ---------------------------------------------------------------------------
__global__ __launch_bounds__(256) void attn_row_kernel(
    const float* __restrict__ CQ, const float* __restrict__ sim_w,
    const float* __restrict__ s2, float* __restrict__ rowm, float* __restrict__ qac)
{
  int i = blockIdx.x;   // 0..4095
  int tid = threadIdx.x;
  const float* Q = CQ + (size_t)4096 * 712;
  __shared__ float crow[712], cw[712], prow[128], red[256];
  const float* ci = CQ + (size_t)i * 712;

  float s1p = 0.f;
  for (int k = tid; k < 712; k += 256) {
    float v = ci[k];
    crow[k] = v;
    cw[k] = v * sim_w[1424 + k];
    s1p += v * sim_w[k];
  }
  red[tid] = s1p;
  __syncthreads();
  for (int s = 128; s > 0; s >>= 1) { if (tid < s) red[tid] += red[tid + s]; __syncthreads(); }
  float s1 = red[0];

  int lane = tid & 63, wv = tid >> 6;
  for (int j = wv; j < 128; j += 4) {
    const float* qj = Q + (size_t)j * 712;
    float s = 0.f;
    for (int k = lane; k < 712; k += 64) s += cw[k] * qj[k];
    s = waveSum(s);
    if (lane == 0) prow[j] = s1 + s2[j] + s;
  }
  __syncthreads();

  float v = (tid < 128) ? prow[tid] : -1e30f;
  red[tid] = v;
  __syncthreads();
  for (int s = 128; s > 0; s >>= 1) { if (tid < s) red[tid] = fmaxf(red[tid], red[tid + s]); __syncthreads(); }
  float m = red[0];
  __syncthreads();
  float e = (tid < 128) ? __expf(prow[tid] - m) : 0.f;
  red[tid] = e;
  __syncthreads();
  for (int s = 128; s > 0; s >>= 1) { if (tid < s) red[tid] += red[tid + s]; __syncthreads(); }
  float denom = red[0];
  if (tid < 128) prow[tid] = e / denom;
  if (tid == 0) rowm[i] = m;
  __syncthreads();

  size_t qb = (size_t)i * 2848;
  for (int k = tid; k < 712; k += 256) {
    float acc = 0.f;
    for (int j = 0; j < 128; ++j) acc += prow[j] * Q[(size_t)j * 712 + k];
    float cv = crow[k];
    qac[qb + k]        = cv;
    qac[qb + 712 + k]  = acc;
    qac[qb + 1424 + k] = cv * acc;
  }
}

// ---------------------------------------------------------------------------
// softmax over a length-4096 vector (single block)
// ---------------------------------------------------------------------------
__global__ __launch_bounds__(256) void softmax_4096(const float* __restrict__ in,
                                                    float* __restrict__ out)
{
  __shared__ float red[256];
  int tid = threadIdx.x;
  float m = -1e30f;
  for (int i = tid; i < 4096; i += 256) m = fmaxf(m, in[i]);
  red[tid] = m;
  __syncthreads();
  for (int s = 128; s > 0; s >>= 1) { if (tid < s) red[tid] = fmaxf(red[tid], red[tid + s]); __syncthreads(); }
  m = red[0];
  __syncthreads();
  float sum = 0.f;
  for (int i = tid; i < 4096; i += 256) sum += __expf(in[i] - m);
  red[tid] = sum;
  __syncthreads();
  for (int s = 128; s > 0; s >>= 1) { if (tid < s) red[tid] += red[tid + s]; __syncthreads(); }
  float denom = red[0];
  for (int i = tid; i < 4096; i += 256) out[i] = __expf(in[i] - m) / denom;
}

// ---------------------------------------------------------------------------
// q2c[k] = sum_i a[i]*C[i,k]
// ---------------------------------------------------------------------------
__global__ __launch_bounds__(256) void q2c_kernel(
    const float* __restrict__ CQ, const float* __restrict__ rowa, float* __restrict__ q2c)
{
  int k = blockIdx.x * 256 + threadIdx.x;
  if (k < 712) {
    float acc = 0.f;
    for (int i = 0; i < 4096; ++i) acc += rowa[i] * CQ[(size_t)i * 712 + k];
    q2c[k] = acc;
  }
}

__global__ __launch_bounds__(256) void qac_finish_kernel(
    const float* __restrict__ CQ, const float* __restrict__ q2c, float* __restrict__ qac)
{
  int i = blockIdx.x;
  int tid = threadIdx.x;
  for (int k = tid; k < 712; k += 256)
    qac[(size_t)i * 2848 + 2136 + k] = CQ[(size_t)i * 712 + k] * q2c[k];
}

__global__ __launch_bounds__(256) void logits_kernel(
    const float* __restrict__ qac, const float* __restrict__ Mx,
    const float* __restrict__ w, float* __restrict__ logits)
{
  int i = blockIdx.x, tid = threadIdx.x;
  __shared__ float red[256];
  float s = 0.f;
  const float* qr = qac + (size_t)i * 2848;
  for (int k = tid; k < 2848; k += 256) s += qr[k] * w[k];
  const float* mr = Mx + (size_t)i * 712;
  for (int k = tid; k < 712; k += 256) s += mr[k] * w[2848 + k];
  red[tid] = s;
  __syncthreads();
  for (int st = 128; st > 0; st >>= 1) { if (tid < st) red[tid] += red[tid + st]; __syncthreads(); }
  if (tid == 0) logits[i] = red[0];
}

// ---------------------------------------------------------------------------
// host side
// ---------------------------------------------------------------------------
extern "C" void kernel_launch(void* const* d_in, const int* in_sizes, int n_in,
                              void* d_out, int out_size, void* d_ws, size_t ws_size,
                              hipStream_t stream)
{
  const int*   chars_ctx = (const int*)d_in[0];
  const int*   chars_qry = (const int*)d_in[1];
  const float* elmo_ctx  = (const float*)d_in[2];
  const float* elmo_qry  = (const float*)d_in[3];
  const float* char_emb  = (const float*)d_in[4];
  const float* conv_w    = (const float*)d_in[5];
  const float* conv_b    = (const float*)d_in[6];
  const float* hw_plain_w = (const float*)d_in[7];
  const float* hw_plain_b = (const float*)d_in[8];
  const float* hw_gate_w  = (const float*)d_in[9];
  const float* hw_gate_b  = (const float*)d_in[10];
  const float* ctx_Wih   = (const float*)d_in[11];
  const float* ctx_Whh   = (const float*)d_in[12];
  const float* ctx_b     = (const float*)d_in[13];
  const float* sim_w     = (const float*)d_in[14];
  const float* mod1_Wih  = (const float*)d_in[15];
  const float* mod1_Whh  = (const float*)d_in[16];
  const float* mod1_b    = (const float*)d_in[17];
  const float* mod2_Wih  = (const float*)d_in[18];
  const float* mod2_Whh  = (const float*)d_in[19];
  const float* mod2_b    = (const float*)d_in[20];
  const float* pos_Wih   = (const float*)d_in[21];
  const float* pos_Whh   = (const float*)d_in[22];
  const float* pos_b     = (const float*)d_in[23];
  const float* pos1_w    = (const float*)d_in[24];
  const float* pos2_w    = (const float*)d_in[25];
  const float* h0_ctx_c  = (const float*)d_in[26];
  const float* h0_ctx_q  = (const float*)d_in[27];
  const float* h0_mod    = (const float*)d_in[28];
  const float* h0_pos    = (const float*)d_in[29];
  float* outp = (float*)d_out;

  float* ws = (float*)d_ws;
  size_t off = 0;
  auto alloc = [&](size_t n) { float* p = ws + off; off += n; return p; };
  float* x_all  = alloc(4224ull * 356);
  float* gbuf   = alloc(4224ull * 356);
  float* pbuf   = alloc(4224ull * 356);
  float* xw_all = alloc(4224ull * 2848);
  float* CQ     = alloc(4224ull * 712);
  float* M1     = alloc(4096ull * 712);
  float* Mm     = alloc(4096ull * 712);
  float* M2     = alloc(4096ull * 712);
  float* qac    = alloc(4096ull * 2848);
  float* s2v    = alloc(128);
  float* rowm   = alloc(4096);
  float* rowa   = alloc(4096);
  float* q2cv   = alloc(1024);
  float* logits = alloc(8192);
  off = (off + 15) & ~(size_t)15;                  // 64B align
  unsigned long long* exbuf = (unsigned long long*)(ws + off);
  // 5 scans x [2 dirs][728 u64]  (712 data + 16 flags); 0xAA poison is an
  // impossible epoch, so no memset needed.
  off += 5ull * 1456 * 2;

  auto cdiv = [](int a, int b) { return (a + b - 1) / b; };

  // 1) char CNN + elmo concat
  cnn_embed_kernel<<<4224, 128, 0, stream>>>(chars_ctx, chars_qry, elmo_ctx, elmo_qry,
                                             char_emb, conv_w, conv_b, x_all);

  // 2) highway x2   (M=4224 %128==0, K=356 %4==0)
  for (int l = 0; l < 2; ++l) {
    gemm128<<<dim3(cdiv(356, 128), 33), 256, 0, stream>>>(
        x_all, hw_gate_w + (size_t)l * 356 * 356, hw_gate_b + l * 356, gbuf, 4224, 356, 356);
    gemm128<<<dim3(cdiv(356, 128), 33), 256, 0, stream>>>(
        x_all, hw_plain_w + (size_t)l * 356 * 356, hw_plain_b + l * 356, pbuf, 4224, 356, 356);
    highway_combine<<<cdiv(4224 * 356, 256), 256, 0, stream>>>(x_all, gbuf, pbuf, 4224 * 356);
  }

  // 3) ctx BiLSTM
  gemm128<<<dim3(cdiv(2848, 128), 33), 256, 0, stream>>>(
      x_all, ctx_Wih, ctx_b, xw_all, 4224, 2848, 356);
  lstm_scan_kernel<<<2 * NWGS, 1024, 0, stream>>>(xw_all, ctx_Whh, h0_ctx_c, CQ, 0, 4096,
                                                  exbuf + 0ull * 1456);
  lstm_scan_kernel<<<2 * NWGS, 1024, 0, stream>>>(xw_all, ctx_Whh, h0_ctx_q, CQ, 4096, 128,
                                                  exbuf + 1ull * 1456);

  // 4) attention
  qdot_kernel<<<128, 64, 0, stream>>>(CQ + 4096ull * 712, sim_w, s2v);
  attn_row_kernel<<<4096, 256, 0, stream>>>(CQ, sim_w, s2v, rowm, qac);
  softmax_4096<<<1, 256, 0, stream>>>(rowm, rowa);
  q2c_kernel<<<cdiv(712, 256), 256, 0, stream>>>(CQ, rowa, q2cv);
  qac_finish_kernel<<<4096, 256, 0, stream>>>(CQ, q2cv, qac);

  // 5) mod1 BiLSTM (input 2848)
  gemm128<<<dim3(cdiv(2848, 128), 32), 256, 0, stream>>>(
      qac, mod1_Wih, mod1_b, xw_all, 4096, 2848, 2848);
  lstm_scan_kernel<<<2 * NWGS, 1024, 0, stream>>>(xw_all, mod1_Whh, h0_mod, M1, 0, 4096,
                                                  exbuf + 2ull * 1456);

  // 6) mod2 BiLSTM (input 712)
  gemm128<<<dim3(cdiv(2848, 128), 32), 256, 0, stream>>>(
      M1, mod2_Wih, mod2_b, xw_all, 4096, 2848, 712);
  lstm_scan_kernel<<<2 * NWGS, 1024, 0, stream>>>(xw_all, mod2_Whh, h0_mod + 712, Mm, 0, 4096,
                                                  exbuf + 3ull * 1456);

  // 7) pos1
  logits_kernel<<<4096, 256, 0, stream>>>(qac, Mm, pos1_w, logits);
  softmax_4096<<<1, 256, 0, stream>>>(logits, outp);

  // 8) pos BiLSTM then pos2
  gemm128<<<dim3(cdiv(2848, 128), 32), 256, 0, stream>>>(
      Mm, pos_Wih, pos_b, xw_all, 4096, 2848, 712);
  lstm_scan_kernel<<<2 * NWGS, 1024, 0, stream>>>(xw_all, pos_Whh, h0_pos, M2, 0, 4096,
                                                  exbuf + 4ull * 1456);
  logits_kernel<<<4096, 256, 0, stream>>>(qac, M2, pos2_w, logits + 4096);
  softmax_4096<<<1, 256, 0, stream>>>(logits + 4096, outp + 4096);

  (void)in_sizes; (void)n_in; (void)out_size; (void)ws_size;
}

// Round 6
// 72955.914 us; speedup vs baseline: 2.6305x; 1.2950x over previous
//
#include <hip/hip_runtime.h>
#include <math.h>

// ---------------------------------------------------------------------------
// helpers
// ---------------------------------------------------------------------------
__device__ __forceinline__ float sigm(float x) { return 1.0f / (1.0f + __expf(-x)); }

__device__ __forceinline__ float waveSum(float v) {
#pragma unroll
  for (int off = 32; off > 0; off >>= 1) v += __shfl_xor(v, off);
  return v;
}

// ---------------------------------------------------------------------------
// char CNN + elmo concat  -> x_all (4224 x 356)
// ---------------------------------------------------------------------------
__global__ __launch_bounds__(128) void cnn_embed_kernel(
    const int* __restrict__ chars_ctx, const int* __restrict__ chars_qry,
    const float* __restrict__ elmo_ctx, const float* __restrict__ elmo_qry,
    const float* __restrict__ char_emb, const float* __restrict__ conv_w,
    const float* __restrict__ conv_b, float* __restrict__ x_all)
{
  int n = blockIdx.x;
  const int*   chars = (n < 4096) ? (chars_ctx + n * 16) : (chars_qry + (n - 4096) * 16);
  const float* elmo  = (n < 4096) ? (elmo_ctx + (size_t)n * 256)
                                  : (elmo_qry + (size_t)(n - 4096) * 256);
  __shared__ float xl[1600];   // [emb_dim=100][pos=16]
  __shared__ int   cidx[16];
  int tid = threadIdx.x;
  if (tid < 16) cidx[tid] = chars[tid];
  __syncthreads();
  for (int e = tid; e < 1600; e += 128) {
    int i = e >> 4, p = e & 15;
    xl[e] = char_emb[cidx[p] * 100 + i];
  }
  __syncthreads();
  if (tid < 100) {
    int o = tid;
    float acc[16];
#pragma unroll
    for (int p = 0; p < 16; ++p) acc[p] = 0.f;
    const float* wo = conv_w + o * 500;
    for (int i = 0; i < 100; ++i) {
      const float* xi = xl + i * 16;
#pragma unroll
      for (int k = 0; k < 5; ++k) {
        float w = wo[i * 5 + k];
#pragma unroll
        for (int p = 0; p < 16; ++p) {
          int src = p + k - 2;
          if (src >= 0 && src < 16) acc[p] += w * xi[src];
        }
      }
    }
    float m = acc[0];
#pragma unroll
    for (int p = 1; p < 16; ++p) m = fmaxf(m, acc[p]);
    x_all[(size_t)n * 356 + o] = m + conv_b[o];
  }
  for (int j = tid; j < 256; j += 128)
    x_all[(size_t)n * 356 + 100 + j] = elmo[j];
}

// ---------------------------------------------------------------------------
// fp32 GEMM:  C[M,N] = A[M,K] @ B[N,K]^T + bias[N]
// 128x128 tile, BK=8, block=256, 8x8 per thread, float4 global + b128 LDS.
// Caller guarantees M % 128 == 0 and K % 4 == 0.
// ---------------------------------------------------------------------------
__global__ __launch_bounds__(256) void gemm128(
    const float* __restrict__ A, const float* __restrict__ B,
    const float* __restrict__ bias, float* __restrict__ C,
    int M, int N, int K)
{
  __shared__ float As[8][132];
  __shared__ float Bs[8][132];
  int tid = threadIdx.x;
  int bm = blockIdx.y * 128, bn = blockIdx.x * 128;
  int r = tid >> 1;            // 0..127
  int c = (tid & 1) * 4;       // 0 or 4
  const float* Arow = A + (size_t)(bm + r) * K;
  const float* Brow = B + (size_t)(bn + r) * K;
  bool brow_ok = (bn + r) < N;
  int m0 = (tid >> 4) * 8;     // 0..120
  int n0 = (tid & 15) * 8;     // 0..120
  float acc[8][8];
#pragma unroll
  for (int i = 0; i < 8; ++i)
#pragma unroll
    for (int j = 0; j < 8; ++j) acc[i][j] = 0.f;

  for (int k0 = 0; k0 < K; k0 += 8) {
    int gk = k0 + c;
    bool kv = gk < K;   // K%4==0: float4 all-or-none
    float4 av = kv ? *(const float4*)(Arow + gk) : float4{0, 0, 0, 0};
    float4 bv = (kv && brow_ok) ? *(const float4*)(Brow + gk) : float4{0, 0, 0, 0};
    __syncthreads();
    As[c + 0][r] = av.x; As[c + 1][r] = av.y; As[c + 2][r] = av.z; As[c + 3][r] = av.w;
    Bs[c + 0][r] = bv.x; Bs[c + 1][r] = bv.y; Bs[c + 2][r] = bv.z; Bs[c + 3][r] = bv.w;
    __syncthreads();
#pragma unroll
    for (int kk = 0; kk < 8; ++kk) {
      float4 a0 = *(const float4*)&As[kk][m0];
      float4 a1 = *(const float4*)&As[kk][m0 + 4];
      float4 b0 = *(const float4*)&Bs[kk][n0];
      float4 b1 = *(const float4*)&Bs[kk][n0 + 4];
      float a[8] = {a0.x, a0.y, a0.z, a0.w, a1.x, a1.y, a1.z, a1.w};
      float b[8] = {b0.x, b0.y, b0.z, b0.w, b1.x, b1.y, b1.z, b1.w};
#pragma unroll
      for (int i = 0; i < 8; ++i)
#pragma unroll
        for (int j = 0; j < 8; ++j) acc[i][j] += a[i] * b[j];
    }
  }
#pragma unroll
  for (int i = 0; i < 8; ++i) {
    int gm = bm + m0 + i;
    float* Cr = C + (size_t)gm * N;
#pragma unroll
    for (int j = 0; j < 8; ++j) {
      int gn = bn + n0 + j;
      if (gn < N) Cr[gn] = acc[i][j] + (bias ? bias[gn] : 0.f);
    }
  }
}

// ---------------------------------------------------------------------------
// highway combine
// ---------------------------------------------------------------------------
__global__ void highway_combine(float* __restrict__ x, const float* __restrict__ g,
                                const float* __restrict__ p, int total)
{
  int i = blockIdx.x * blockDim.x + threadIdx.x;
  if (i < total) {
    float gg = sigm(g[i]);
    float pp = fmaxf(p[i], 0.f);
    x[i] = gg * pp + (1.f - gg) * x[i];
  }
}

// ---------------------------------------------------------------------------
// persistent BiLSTM scan, v6 = v2 protocol (proven) + self-poll skip + backoff.
// grid = 32 blocks (dir = blockIdx&1, wg = blockIdx>>1, 16 WGs/dir), block=512.
// Each WG owns SLICE=23 hidden units (92 Whh rows) in VGPRs. Each step,
// every hidden unit is published as ONE 64-bit word { epoch:32 | h_bits:32 }
// with a relaxed agent-scope atomic store into a parity-double-buffered
// exchange array; consumers poll their own word with relaxed atomic loads
// (fine-grained: each proceeds the moment its word lands). Producers skip
// polling their own slice (h_lds written directly). A light s_sleep backoff
// after 32 stale polls damps fabric congestion spikes.
// ---------------------------------------------------------------------------
#define NWG 16
#define SLICE 23   // 16*23 = 368 >= 356

__global__ __launch_bounds__(512, 1) void lstm_scan_kernel(
    const float* __restrict__ xw, const float* __restrict__ whh,
    const float* __restrict__ h0, float* __restrict__ out,
    int row0, int N, unsigned long long* exbuf)
{
  const int tid  = threadIdx.x;
  const int dir  = blockIdx.x & 1;
  const int wg   = blockIdx.x >> 1;
  const int lane = tid & 63;
  const int wv   = tid >> 6;          // 0..7
  const int j0   = wg * SLICE;
  const float* whh_d = whh + (size_t)dir * 1424 * 356;
  const float* h0_d  = h0 + dir * 356;
  const int xcol0 = dir * 1424;
  const int ocol0 = dir * 356;
  unsigned long long* exd = exbuf + dir * 712;   // [parity][356]

  __shared__ float h_lds[384];
  __shared__ float z_lds[4 * SLICE];   // [gate][jj]

  // z-duty: tid < 92 handles one (gate,jj) element of z/xw
  const bool zduty = (tid < 4 * SLICE);
  bool zvalid = false;
  size_t xcol = 0;
  if (zduty) {
    int zgate = tid / SLICE, zjj = tid % SLICE, zj = j0 + zjj;
    zvalid = (zj < 356);
    xcol = (size_t)(xcol0 + zgate * 356 + zj);
  }

  // Whh slice -> registers: wave wv, q=0..11 -> rr = wv*12+q
  float wreg[12][6];
#pragma unroll
  for (int q = 0; q < 12; ++q) {
    int rr = wv * 12 + q;
    bool rv = (rr < 4 * SLICE);
    int gate = rv ? (rr / SLICE) : 0, jj = rv ? (rr % SLICE) : 0;
    int j = j0 + jj;
    bool v = rv && (j < 356);
    int row_g = gate * 356 + j;
#pragma unroll
    for (int ii = 0; ii < 6; ++ii) {
      int k = lane + ii * 64;
      wreg[q][ii] = (v && k < 356) ? whh_d[(size_t)row_g * 356 + k] : 0.f;
    }
  }

  // init h (pad zeroed), per-thread c for owned unit
  for (int k = tid; k < 384; k += 512) h_lds[k] = (k < 356) ? h0_d[k] : 0.f;
  float c_reg = 0.f;
  if (tid < SLICE) { int j = j0 + tid; if (j < 356) c_reg = h0_d[j]; }

  // preload xw for t=0
  float xw_cur = 0.f;
  {
    int row = dir ? (N - 1) : 0;
    if (zvalid) xw_cur = xw[(size_t)(row0 + row) * 2848 + xcol];
  }
  __syncthreads();

  for (int t = 0; t < N; ++t) {
    int row = dir ? (N - 1 - t) : t;
    size_t grow = (size_t)(row0 + row);
    int par = t & 1;
    unsigned tgt = (unsigned)(t + 1);

    // stage A: z init from prefetched xw; issue prefetch for t+1
    if (zduty) z_lds[tid] = zvalid ? xw_cur : 0.f;
    float xw_nx = 0.f;
    {
      int tn = (t + 1 < N) ? (t + 1) : (N - 1);
      int rown = dir ? (N - 1 - tn) : tn;
      if (zvalid) xw_nx = xw[(size_t)(row0 + rown) * 2848 + xcol];
    }
    __syncthreads();

    // stage B: z[rr] += Whh_row . h
    {
      float hv[6];
#pragma unroll
      for (int ii = 0; ii < 6; ++ii) hv[ii] = h_lds[lane + ii * 64];
#pragma unroll
      for (int q = 0; q < 12; ++q) {
        float s = 0.f;
#pragma unroll
        for (int ii = 0; ii < 6; ++ii) s += wreg[q][ii] * hv[ii];
        s = waveSum(s);
        int rr = wv * 12 + q;
        if (lane == 0 && rr < 4 * SLICE) z_lds[rr] += s;
      }
    }
    __syncthreads();

    // stage C: gate update + publish packed (epoch|h); own slice -> h_lds
    if (tid < SLICE) {
      int j = j0 + tid;
      if (j < 356) {
        float zi = z_lds[tid], zf = z_lds[SLICE + tid];
        float zg = z_lds[2 * SLICE + tid], zo = z_lds[3 * SLICE + tid];
        float cc = sigm(zf) * c_reg + sigm(zi) * tanhf(zg);
        float h = sigm(zo) * tanhf(cc);
        c_reg = cc;
        out[grow * 712 + ocol0 + j] = h;
        h_lds[j] = h;   // own slice fresh locally — no self round trip
        unsigned long long pk =
            ((unsigned long long)tgt << 32) |
            (unsigned long long)__float_as_uint(h);
        __hip_atomic_store(&exd[(size_t)par * 356 + j], pk,
                           __ATOMIC_RELAXED, __HIP_MEMORY_SCOPE_AGENT);
      }
    }

    // stage D: poll foreign words until fresh, deposit into h_lds
    if (tid < 356 && (tid < j0 || tid >= j0 + SLICE)) {
      unsigned long long* p = &exd[(size_t)par * 356 + tid];
      unsigned long long v;
      int spins = 0;
      for (;;) {
        v = __hip_atomic_load(p, __ATOMIC_RELAXED, __HIP_MEMORY_SCOPE_AGENT);
        if ((unsigned)(v >> 32) == tgt) break;
        if (++spins > 32) __builtin_amdgcn_s_sleep(2);   // damp fabric pressure
      }
      h_lds[tid] = __uint_as_float((unsigned)v);
    }
    __syncthreads();

    xw_cur = xw_nx;
  }
}

// ---------------------------------------------------------------------------
// attention: s2[j] = Q[j] . w_q
// ---------------------------------------------------------------------------
__global__ __launch_bounds__(64) void qdot_kernel(
    const float* __restrict__ Q, const float* __restrict__ sim_w, float* __restrict__ s2)
{
  int j = blockIdx.x;
  int lane = threadIdx.x;
  const float* q  = Q + (size_t)j * 712;
  const float* wq = sim_w + 712;
  float s = 0.f;
  for (int k = lane; k < 712; k += 64) s += q[k] * wq[k];
  s = waveSum(s);
  if (lane == 0) s2[j] = s;
}

// ---------------------------------------------------------------------------
// per-context-row attention + qac[0,2136)
// ---------------------------------------------------------------------------
__global__ __launch_bounds__(256) void attn_row_kernel(
    const float* __restrict__ CQ, const float* __restrict__ sim_w,
    const float* __restrict__ s2, float* __restrict__ rowm, float* __restrict__ qac)
{
  int i = blockIdx.x;   // 0..4095
  int tid = threadIdx.x;
  const float* Q = CQ + (size_t)4096 * 712;
  __shared__ float crow[712], cw[712], prow[128], red[256];
  const float* ci = CQ + (size_t)i * 712;

  float s1p = 0.f;
  for (int k = tid; k < 712; k += 256) {
    float v = ci[k];
    crow[k] = v;
    cw[k] = v * sim_w[1424 + k];
    s1p += v * sim_w[k];
  }
  red[tid] = s1p;
  __syncthreads();
  for (int s = 128; s > 0; s >>= 1) { if (tid < s) red[tid] += red[tid + s]; __syncthreads(); }
  float s1 = red[0];

  int lane = tid & 63, wv = tid >> 6;
  for (int j = wv; j < 128; j += 4) {
    const float* qj = Q + (size_t)j * 712;
    float s = 0.f;
    for (int k = lane; k < 712; k += 64) s += cw[k] * qj[k];
    s = waveSum(s);
    if (lane == 0) prow[j] = s1 + s2[j] + s;
  }
  __syncthreads();

  float v = (tid < 128) ? prow[tid] : -1e30f;
  red[tid] = v;
  __syncthreads();
  for (int s = 128; s > 0; s >>= 1) { if (tid < s) red[tid] = fmaxf(red[tid], red[tid + s]); __syncthreads(); }
  float m = red[0];
  __syncthreads();
  float e = (tid < 128) ? __expf(prow[tid] - m) : 0.f;
  red[tid] = e;
  __syncthreads();
  for (int s = 128; s > 0; s >>= 1) { if (tid < s) red[tid] += red[tid + s]; __syncthreads(); }
  float denom = red[0];
  if (tid < 128) prow[tid] = e / denom;
  if (tid == 0) rowm[i] = m;
  __syncthreads();

  size_t qb = (size_t)i * 2848;
  for (int k = tid; k < 712; k += 256) {
    float acc = 0.f;
    for (int j = 0; j < 128; ++j) acc += prow[j] * Q[(size_t)j * 712 + k];
    float cv = crow[k];
    qac[qb + k]        = cv;
    qac[qb + 712 + k]  = acc;
    qac[qb + 1424 + k] = cv * acc;
  }
}

// ---------------------------------------------------------------------------
// softmax over a length-4096 vector (single block)
// ---------------------------------------------------------------------------
__global__ __launch_bounds__(256) void softmax_4096(const float* __restrict__ in,
                                                    float* __restrict__ out)
{
  __shared__ float red[256];
  int tid = threadIdx.x;
  float m = -1e30f;
  for (int i = tid; i < 4096; i += 256) m = fmaxf(m, in[i]);
  red[tid] = m;
  __syncthreads();
  for (int s = 128; s > 0; s >>= 1) { if (tid < s) red[tid] = fmaxf(red[tid], red[tid + s]); __syncthreads(); }
  m = red[0];
  __syncthreads();
  float sum = 0.f;
  for (int i = tid; i < 4096; i += 256) sum += __expf(in[i] - m);
  red[tid] = sum;
  __syncthreads();
  for (int s = 128; s > 0; s >>= 1) { if (tid < s) red[tid] += red[tid + s]; __syncthreads(); }
  float denom = red[0];
  for (int i = tid; i < 4096; i += 256) out[i] = __expf(in[i] - m) / denom;
}

// ---------------------------------------------------------------------------
// q2c[k] = sum_i a[i]*C[i,k]
// ---------------------------------------------------------------------------
__global__ __launch_bounds__(256) void q2c_kernel(
    const float* __restrict__ CQ, const float* __restrict__ rowa, float* __restrict__ q2c)
{
  int k = blockIdx.x * 256 + threadIdx.x;
  if (k < 712) {
    float acc = 0.f;
    for (int i = 0; i < 4096; ++i) acc += rowa[i] * CQ[(size_t)i * 712 + k];
    q2c[k] = acc;
  }
}

__global__ __launch_bounds__(256) void qac_finish_kernel(
    const float* __restrict__ CQ, const float* __restrict__ q2c, float* __restrict__ qac)
{
  int i = blockIdx.x;
  int tid = threadIdx.x;
  for (int k = tid; k < 712; k += 256)
    qac[(size_t)i * 2848 + 2136 + k] = CQ[(size_t)i * 712 + k] * q2c[k];
}

__global__ __launch_bounds__(256) void logits_kernel(
    const float* __restrict__ qac, const float* __restrict__ Mx,
    const float* __restrict__ w, float* __restrict__ logits)
{
  int i = blockIdx.x, tid = threadIdx.x;
  __shared__ float red[256];
  float s = 0.f;
  const float* qr = qac + (size_t)i * 2848;
  for (int k = tid; k < 2848; k += 256) s += qr[k] * w[k];
  const float* mr = Mx + (size_t)i * 712;
  for (int k = tid; k < 712; k += 256) s += mr[k] * w[2848 + k];
  red[tid] = s;
  __syncthreads();
  for (int st = 128; st > 0; st >>= 1) { if (tid < st) red[tid] += red[tid + st]; __syncthreads(); }
  if (tid == 0) logits[i] = red[0];
}

// ---------------------------------------------------------------------------
// host side
// ---------------------------------------------------------------------------
extern "C" void kernel_launch(void* const* d_in, const int* in_sizes, int n_in,
                              void* d_out, int out_size, void* d_ws, size_t ws_size,
                              hipStream_t stream)
{
  const int*   chars_ctx = (const int*)d_in[0];
  const int*   chars_qry = (const int*)d_in[1];
  const float* elmo_ctx  = (const float*)d_in[2];
  const float* elmo_qry  = (const float*)d_in[3];
  const float* char_emb  = (const float*)d_in[4];
  const float* conv_w    = (const float*)d_in[5];
  const float* conv_b    = (const float*)d_in[6];
  const float* hw_plain_w = (const float*)d_in[7];
  const float* hw_plain_b = (const float*)d_in[8];
  const float* hw_gate_w  = (const float*)d_in[9];
  const float* hw_gate_b  = (const float*)d_in[10];
  const float* ctx_Wih   = (const float*)d_in[11];
  const float* ctx_Whh   = (const float*)d_in[12];
  const float* ctx_b     = (const float*)d_in[13];
  const float* sim_w     = (const float*)d_in[14];
  const float* mod1_Wih  = (const float*)d_in[15];
  const float* mod1_Whh  = (const float*)d_in[16];
  const float* mod1_b    = (const float*)d_in[17];
  const float* mod2_Wih  = (const float*)d_in[18];
  const float* mod2_Whh  = (const float*)d_in[19];
  const float* mod2_b    = (const float*)d_in[20];
  const float* pos_Wih   = (const float*)d_in[21];
  const float* pos_Whh   = (const float*)d_in[22];
  const float* pos_b     = (const float*)d_in[23];
  const float* pos1_w    = (const float*)d_in[24];
  const float* pos2_w    = (const float*)d_in[25];
  const float* h0_ctx_c  = (const float*)d_in[26];
  const float* h0_ctx_q  = (const float*)d_in[27];
  const float* h0_mod    = (const float*)d_in[28];
  const float* h0_pos    = (const float*)d_in[29];
  float* outp = (float*)d_out;

  float* ws = (float*)d_ws;
  size_t off = 0;
  auto alloc = [&](size_t n) { float* p = ws + off; off += n; return p; };
  float* x_all  = alloc(4224ull * 356);
  float* gbuf   = alloc(4224ull * 356);
  float* pbuf   = alloc(4224ull * 356);
  float* xw_all = alloc(4224ull * 2848);
  float* CQ     = alloc(4224ull * 712);
  float* M1     = alloc(4096ull * 712);
  float* Mm     = alloc(4096ull * 712);
  float* M2     = alloc(4096ull * 712);
  float* qac    = alloc(4096ull * 2848);
  float* s2v    = alloc(128);
  float* rowm   = alloc(4096);
  float* rowa   = alloc(4096);
  float* q2cv   = alloc(1024);
  float* logits = alloc(8192);
  off = (off + 1) & ~(size_t)1;                    // 8B align
  unsigned long long* exbuf = (unsigned long long*)(ws + off);
  // 5 scans x [2 dirs][2 parity][356] u64 — 0xAA poison can never equal a
  // valid epoch (t+1 <= 4096), so no memset needed.
  off += 5ull * 1424 * 2;

  auto cdiv = [](int a, int b) { return (a + b - 1) / b; };

  // 1) char CNN + elmo concat
  cnn_embed_kernel<<<4224, 128, 0, stream>>>(chars_ctx, chars_qry, elmo_ctx, elmo_qry,
                                             char_emb, conv_w, conv_b, x_all);

  // 2) highway x2   (M=4224 %128==0, K=356 %4==0)
  for (int l = 0; l < 2; ++l) {
    gemm128<<<dim3(cdiv(356, 128), 33), 256, 0, stream>>>(
        x_all, hw_gate_w + (size_t)l * 356 * 356, hw_gate_b + l * 356, gbuf, 4224, 356, 356);
    gemm128<<<dim3(cdiv(356, 128), 33), 256, 0, stream>>>(
        x_all, hw_plain_w + (size_t)l * 356 * 356, hw_plain_b + l * 356, pbuf, 4224, 356, 356);
    highway_combine<<<cdiv(4224 * 356, 256), 256, 0, stream>>>(x_all, gbuf, pbuf, 4224 * 356);
  }

  // 3) ctx BiLSTM
  gemm128<<<dim3(cdiv(2848, 128), 33), 256, 0, stream>>>(
      x_all, ctx_Wih, ctx_b, xw_all, 4224, 2848, 356);
  lstm_scan_kernel<<<2 * NWG, 512, 0, stream>>>(xw_all, ctx_Whh, h0_ctx_c, CQ, 0, 4096,
                                                exbuf + 0ull * 1424);
  lstm_scan_kernel<<<2 * NWG, 512, 0, stream>>>(xw_all, ctx_Whh, h0_ctx_q, CQ, 4096, 128,
                                                exbuf + 1ull * 1424);

  // 4) attention
  qdot_kernel<<<128, 64, 0, stream>>>(CQ + 4096ull * 712, sim_w, s2v);
  attn_row_kernel<<<4096, 256, 0, stream>>>(CQ, sim_w, s2v, rowm, qac);
  softmax_4096<<<1, 256, 0, stream>>>(rowm, rowa);
  q2c_kernel<<<cdiv(712, 256), 256, 0, stream>>>(CQ, rowa, q2cv);
  qac_finish_kernel<<<4096, 256, 0, stream>>>(CQ, q2cv, qac);

  // 5) mod1 BiLSTM (input 2848)
  gemm128<<<dim3(cdiv(2848, 128), 32), 256, 0, stream>>>(
      qac, mod1_Wih, mod1_b, xw_all, 4096, 2848, 2848);
  lstm_scan_kernel<<<2 * NWG, 512, 0, stream>>>(xw_all, mod1_Whh, h0_mod, M1, 0, 4096,
                                                exbuf + 2ull * 1424);

  // 6) mod2 BiLSTM (input 712)
  gemm128<<<dim3(cdiv(2848, 128), 32), 256, 0, stream>>>(
      M1, mod2_Wih, mod2_b, xw_all, 4096, 2848, 712);
  lstm_scan_kernel<<<2 * NWG, 512, 0, stream>>>(xw_all, mod2_Whh, h0_mod + 712, Mm, 0, 4096,
                                                exbuf + 3ull * 1424);

  // 7) pos1
  logits_kernel<<<4096, 256, 0, stream>>>(qac, Mm, pos1_w, logits);
  softmax_4096<<<1, 256, 0, stream>>>(logits, outp);

  // 8) pos BiLSTM then pos2
  gemm128<<<dim3(cdiv(2848, 128), 32), 256, 0, stream>>>(
      Mm, pos_Wih, pos_b, xw_all, 4096, 2848, 712);
  lstm_scan_kernel<<<2 * NWG, 512, 0, stream>>>(xw_all, pos_Whh, h0_pos, M2, 0, 4096,
                                                exbuf + 4ull * 1424);
  logits_kernel<<<4096, 256, 0, stream>>>(qac, M2, pos2_w, logits + 4096);
  softmax_4096<<<1, 256, 0, stream>>>(logits + 4096, outp + 4096);

  (void)in_sizes; (void)n_in; (void)out_size; (void)ws_size;
}